// Round 11
// baseline (1917.184 us; speedup 1.0000x reference)
//
#include <hip/hip_runtime.h>
#include <hip/hip_bf16.h>

// VanillaRNN: S=512,B=256,E=256,H=1024,C=10, vocab=10
// R11 = R6 + all-wave direct poll of the single per-step flag (removes the
// tid0-detect -> barrier broadcast hop; one flag line, wave-uniform loads =
// one broadcast transaction per poll, so fan-in stays low, unlike R8) +
// zero_flags fused into packw_k (one fewer launch).
// Everything else identical to R6 (champion: 2.3us/step).

typedef __attribute__((ext_vector_type(8))) short short8;
typedef __attribute__((ext_vector_type(4))) float f32x4;

#define S_LEN 512
#define HDIM  1024
#define NVOC  10

// ws layout (bytes)
#define OFF_WF    0u          // 1024*1024 bf16 frag-packed = 2 MB
#define OFF_PROJ  2097152u    // 10*1024 f32
#define OFF_STBF  2138112u    // 2 x 256*1024 bf16 (ping-pong)
#define OFF_STF   3186688u    // 256*1024 f32
#define OFF_FLAGS 4235264u    // 16 groups * 512 steps u32
#define OFF_XCD   4268032u    // 16*16 u32 xcd map
#define OFF_SETUP 4269056u    // 16 u32 setup counters

// proj[v][h] = sum_e emb[v][e]*W_hx[e][h] + b_h[h]
__global__ void proj_k(const float* __restrict__ emb, const float* __restrict__ W_hx,
                       const float* __restrict__ b_h, float* __restrict__ proj) {
    int id = blockIdx.x * 256 + threadIdx.x;
    if (id >= NVOC * HDIM) return;
    int v = id >> 10, h = id & 1023;
    float a = b_h[h];
    #pragma unroll 8
    for (int e = 0; e < 256; ++e) a += emb[v * 256 + e] * W_hx[e * HDIM + h];
    proj[id] = a;
}

static __device__ inline unsigned short f2bf(float f) {
    unsigned u = __builtin_bit_cast(unsigned, f);
    return (unsigned short)((u + 0x7fffu + ((u >> 16) & 1u)) >> 16);
}

// pack W_hh[k][n] (f32) -> Wf frag layout: [nt(64)][kk(32)][lane(64)][8] bf16
// lane l of (nt,kk) holds W[kk*32 + (l>>4)*8 + j][nt*16 + (l&15)]
// Also zeroes the flag/xcd/setup region (fused zero_flags).
__global__ void packw_k(const float* __restrict__ W_hh, unsigned short* __restrict__ Wf,
                        unsigned int* __restrict__ flags) {
    int idx = blockIdx.x * 256 + threadIdx.x;   // 131072 total
    if (idx < 16 * S_LEN + 256 + 16) flags[idx] = 0u;
    int lane = idx & 63, kk = (idx >> 6) & 31, nt = idx >> 11;
    int k0 = kk * 32 + (lane >> 4) * 8;
    int col = nt * 16 + (lane & 15);
    short8 v;
    #pragma unroll
    for (int j = 0; j < 8; ++j) v[j] = (short)f2bf(W_hh[(k0 + j) * HDIM + col]);
    *(short8*)(Wf + (size_t)idx * 8) = v;
}

__global__ __launch_bounds__(256, 1) void rnn_steps_k(
    const int* __restrict__ x, const unsigned short* __restrict__ Wf,
    const float* __restrict__ proj, unsigned short* __restrict__ stbf,
    float* __restrict__ stf, unsigned int* __restrict__ flags,
    unsigned int* __restrict__ xcdmap, unsigned int* __restrict__ setupf)
{
    const int bid = blockIdx.x;
    // bid%8 round-robin puts group g's 16 wgs on XCD g>>1 (heuristic; verified
    // at runtime below — correctness does not depend on it)
    const int g   = ((bid & 7) << 1) | ((bid >> 3) & 1);   // 0..15 batch-group
    const int wgn = bid >> 4;                              // 0..15 col-block
    const int tid = threadIdx.x;
    const int wave = tid >> 6, lane = tid & 63;
    const int b0 = g << 4;
    const int nt = (wgn << 2) + wave;      // global 16-col tile index
    const int n0 = nt << 4;                // col base (per wave)
    const int wg_n0 = wgn << 6;            // col base (per workgroup)
    const int row = lane & 15;
    const int kl  = lane >> 4;

    __shared__ __align__(16) char Abuf[32768];     // 16 x 1024 bf16 (swizzled)
    __shared__ unsigned char xl[S_LEN * 16];
    __shared__ float pl[NVOC * 64];
    __shared__ unsigned uni_sh;

    // --- XCD detection + group-uniformity check (once) ---
    unsigned xcd;
    asm("s_getreg_b32 %0, hwreg(HW_REG_XCC_ID)" : "=s"(xcd));
    if (tid == 0) {
        xcdmap[(g << 4) + wgn] = xcd;
        __hip_atomic_fetch_add(setupf + g, 1u, __ATOMIC_RELEASE, __HIP_MEMORY_SCOPE_AGENT);
        while (__hip_atomic_load(setupf + g, __ATOMIC_ACQUIRE, __HIP_MEMORY_SCOPE_AGENT) < 16u) {}
        unsigned u = 1u;
        for (int i = 0; i < 16; ++i) {
            unsigned v = __hip_atomic_load(xcdmap + (g << 4) + i,
                                           __ATOMIC_RELAXED, __HIP_MEMORY_SCOPE_AGENT);
            u &= (unsigned)(v == xcd);
        }
        uni_sh = u;
    }

    for (int i = tid; i < S_LEN * 16; i += 256)
        xl[i] = (unsigned char)x[((i >> 4) << 8) + b0 + (i & 15)];
    for (int i = tid; i < NVOC * 64; i += 256)
        pl[i] = proj[(i >> 6) * HDIM + wg_n0 + (i & 63)];

    // B fragments: wave's K=1024 x 16-col slice of W_hh, resident in regs
    short8 bfr[32];
    const short8* wp = (const short8*)Wf;
    #pragma unroll
    for (int kk = 0; kk < 32; ++kk)
        bfr[kk] = wp[((nt << 5) + kk) * 64 + lane];

    __syncthreads();
    const bool uniform = (uni_sh != 0u);

    const int sw = (row & 7) << 4;   // XOR swizzle (bank-conflict fix)
    const int abase = row << 11;
    const int klb = kl << 4;

    for (int s = 0; s < S_LEN; ++s) {
        f32x4 acc0 = {0.f, 0.f, 0.f, 0.f};
        f32x4 acc1 = acc0, acc2 = acc0, acc3 = acc0;
        if (s > 0) {
            // ALL-WAVE direct poll of the single per-step flag: each wave
            // starts staging at its own detect (no tid0 gate, no barrier #1).
            // Wave-uniform address -> one broadcast transaction per poll.
            {
                const unsigned int* fp = flags + (g << 9) + (s - 1);
                while (__hip_atomic_load(fp, __ATOMIC_RELAXED, __HIP_MEMORY_SCOPE_AGENT) < 16u) {}
            }
            // stage prev state tile (16 rows x 2048 B), pre-swizzled source
            const char* src = (const char*)stbf + (((s - 1) & 1) << 19) + (g << 15);
            if (uniform) {
                // FAST: producers share this XCD's L2 -> SC0 only (bypass L1)
                #pragma unroll
                for (int it = 0; it < 8; ++it) {
                    int o = (it * 256 + tid) * 16;
                    int arow = o >> 11;
                    int soff = (arow << 11) + ((o & 2047) ^ ((arow & 7) << 4));
                    __builtin_amdgcn_global_load_lds(
                        (const __attribute__((address_space(1))) void*)(src + soff),
                        (__attribute__((address_space(3))) void*)(Abuf + it * 4096 + wave * 1024),
                        16, 0, 1);
                }
            } else {
                // FALLBACK: cross-XCD -> read MALL (SC0|SC1), R5-proven
                #pragma unroll
                for (int it = 0; it < 8; ++it) {
                    int o = (it * 256 + tid) * 16;
                    int arow = o >> 11;
                    int soff = (arow << 11) + ((o & 2047) ^ ((arow & 7) << 4));
                    __builtin_amdgcn_global_load_lds(
                        (const __attribute__((address_space(1))) void*)(src + soff),
                        (__attribute__((address_space(3))) void*)(Abuf + it * 4096 + wave * 1024),
                        16, 0, 17);
                }
            }
            __syncthreads();   // staging complete across all waves
            #pragma unroll
            for (int kk = 0; kk < 32; kk += 4) {   // 4 independent acc chains
                short8 a0 = *(const short8*)(Abuf + abase + ((((kk + 0) << 6) + klb) ^ sw));
                short8 a1 = *(const short8*)(Abuf + abase + ((((kk + 1) << 6) + klb) ^ sw));
                short8 a2 = *(const short8*)(Abuf + abase + ((((kk + 2) << 6) + klb) ^ sw));
                short8 a3 = *(const short8*)(Abuf + abase + ((((kk + 3) << 6) + klb) ^ sw));
                acc0 = __builtin_amdgcn_mfma_f32_16x16x32_bf16(a0, bfr[kk + 0], acc0, 0, 0, 0);
                acc1 = __builtin_amdgcn_mfma_f32_16x16x32_bf16(a1, bfr[kk + 1], acc1, 0, 0, 0);
                acc2 = __builtin_amdgcn_mfma_f32_16x16x32_bf16(a2, bfr[kk + 2], acc2, 0, 0, 0);
                acc3 = __builtin_amdgcn_mfma_f32_16x16x32_bf16(a3, bfr[kk + 3], acc3, 0, 0, 0);
            }
        }
        f32x4 accs = acc0 + acc1 + acc2 + acc3;
        #pragma unroll
        for (int j = 0; j < 4; ++j) {
            int r = (kl << 2) + j;
            int xv = xl[(s << 4) + r];
            float p = pl[(xv << 6) + (wave << 4) + row];
            float z = accs[j] + p;
            z = fminf(15.f, fmaxf(-15.f, z));
            float e = exp2f(z * 2.885390082f);
            float th = (e - 1.f) / (e + 1.f);
            if (s < S_LEN - 1) {
                stbf[((s & 1) << 18) + ((b0 + r) << 10) + n0 + row] = f2bf(th);
            } else {
                stf[((b0 + r) << 10) + n0 + row] = th;
            }
        }
        if (s < S_LEN - 1) {
            __syncthreads();  // drains all waves' stores (vmcnt0 before barrier)
            if (tid == 0) {
                if (uniform) {
                    // same-XCD: state visible in shared L2 after drain
                    __hip_atomic_fetch_add(flags + (g << 9) + s, 1u,
                                           __ATOMIC_RELAXED, __HIP_MEMORY_SCOPE_AGENT);
                } else {
                    // cross-XCD: release pushes state to MALL first
                    __hip_atomic_fetch_add(flags + (g << 9) + s, 1u,
                                           __ATOMIC_RELEASE, __HIP_MEMORY_SCOPE_AGENT);
                }
            }
        }
    }
}

// out[b][c] = state_f32[b] @ W_ph[:,c] + b_p[c]
__global__ void outproj_k(const float* __restrict__ stf, const float* __restrict__ W_ph,
                          const float* __restrict__ b_p, float* __restrict__ out) {
    int b = blockIdx.x, t = threadIdx.x;
    float acc[10];
    #pragma unroll
    for (int c = 0; c < 10; ++c) acc[c] = 0.f;
    for (int h = t; h < HDIM; h += 256) {
        float sv = stf[b * HDIM + h];
        const float* w = W_ph + h * 10;
        #pragma unroll
        for (int c = 0; c < 10; ++c) acc[c] += sv * w[c];
    }
    __shared__ float red[256][10];
    #pragma unroll
    for (int c = 0; c < 10; ++c) red[t][c] = acc[c];
    __syncthreads();
    for (int off = 128; off > 0; off >>= 1) {
        if (t < off) {
            #pragma unroll
            for (int c = 0; c < 10; ++c) red[t][c] += red[t + off][c];
        }
        __syncthreads();
    }
    if (t < 10) out[b * 10 + t] = red[0][t] + b_p[t];
}

extern "C" void kernel_launch(void* const* d_in, const int* in_sizes, int n_in,
                              void* d_out, int out_size, void* d_ws, size_t ws_size,
                              hipStream_t stream) {
    const int*   x    = (const int*)d_in[0];
    const float* emb  = (const float*)d_in[1];
    const float* W_hx = (const float*)d_in[2];
    const float* W_hh = (const float*)d_in[3];
    const float* W_ph = (const float*)d_in[4];
    const float* b_h  = (const float*)d_in[5];
    const float* b_p  = (const float*)d_in[6];

    char* ws = (char*)d_ws;
    unsigned short* Wf     = (unsigned short*)(ws + OFF_WF);
    float*          proj   = (float*)(ws + OFF_PROJ);
    unsigned short* stbf   = (unsigned short*)(ws + OFF_STBF);
    float*          stf    = (float*)(ws + OFF_STF);
    unsigned int*   flags  = (unsigned int*)(ws + OFF_FLAGS);
    unsigned int*   xcdmap = (unsigned int*)(ws + OFF_XCD);
    unsigned int*   setupf = (unsigned int*)(ws + OFF_SETUP);

    proj_k<<<40, 256, 0, stream>>>(emb, W_hx, b_h, proj);
    packw_k<<<512, 256, 0, stream>>>(W_hh, Wf, flags);
    rnn_steps_k<<<256, 256, 0, stream>>>(x, Wf, proj, stbf, stf, flags, xcdmap, setupf);
    outproj_k<<<256, 256, 0, stream>>>(stf, W_ph, b_p, (float*)d_out);
}

// Round 12
// 1227.024 us; speedup vs baseline: 1.5625x; 1.5625x over previous
//
#include <hip/hip_runtime.h>
#include <hip/hip_bf16.h>

// VanillaRNN: S=512,B=256,E=256,H=1024,C=10, vocab=10
// R12 = R6 with producer-side de-serialization ONLY:
//  - per-(group,step) flag line: 16 u32 slots packed in ONE 64B line
//  - producers: parallel plain atomic STORES (no RMW read-return, no
//    serialized chain) — relaxed fast-path / release fallback
//  - consumer: wave 0 polls slots (lane&15) -> 16 addrs coalesce to ONE
//    64B L2 transaction per iteration; __any; then the proven
//    tid-gate __syncthreads broadcast (R6 structure untouched)
// Consumer fan-in lesson (R7/R8/R11): keep ONE polling wave, ONE line.

typedef __attribute__((ext_vector_type(8))) short short8;
typedef __attribute__((ext_vector_type(4))) float f32x4;

#define S_LEN 512
#define HDIM  1024
#define NVOC  10

// ws layout (bytes)
#define OFF_WF    0u          // 1024*1024 bf16 frag-packed = 2 MB
#define OFF_PROJ  2097152u    // 10*1024 f32
#define OFF_STBF  2138112u    // 2 x 256*1024 bf16 (ping-pong)
#define OFF_STF   3186688u    // 256*1024 f32
#define OFF_FLAGS 4235264u    // 16 groups * 512 steps * 64B line = 512 KB
#define OFF_XCD   4759552u    // 16*16 u32 xcd map
#define OFF_SETUP 4760576u    // 16 u32 setup counters

// proj[v][h] = sum_e emb[v][e]*W_hx[e][h] + b_h[h]
__global__ void proj_k(const float* __restrict__ emb, const float* __restrict__ W_hx,
                       const float* __restrict__ b_h, float* __restrict__ proj) {
    int id = blockIdx.x * 256 + threadIdx.x;
    if (id >= NVOC * HDIM) return;
    int v = id >> 10, h = id & 1023;
    float a = b_h[h];
    #pragma unroll 8
    for (int e = 0; e < 256; ++e) a += emb[v * 256 + e] * W_hx[e * HDIM + h];
    proj[id] = a;
}

static __device__ inline unsigned short f2bf(float f) {
    unsigned u = __builtin_bit_cast(unsigned, f);
    return (unsigned short)((u + 0x7fffu + ((u >> 16) & 1u)) >> 16);
}

// pack W_hh[k][n] (f32) -> Wf frag layout: [nt(64)][kk(32)][lane(64)][8] bf16
// lane l of (nt,kk) holds W[kk*32 + (l>>4)*8 + j][nt*16 + (l&15)]
// Also zeroes the flag region (131072 u32 = exactly one thread each) + aux.
__global__ void packw_k(const float* __restrict__ W_hh, unsigned short* __restrict__ Wf,
                        unsigned int* __restrict__ flags, unsigned int* __restrict__ aux) {
    int idx = blockIdx.x * 256 + threadIdx.x;   // 131072 total
    flags[idx] = 0u;                            // 16*512*16 u32 = 512 KB
    if (idx < 272) aux[idx] = 0u;               // xcdmap(256) + setup(16)
    int lane = idx & 63, kk = (idx >> 6) & 31, nt = idx >> 11;
    int k0 = kk * 32 + (lane >> 4) * 8;
    int col = nt * 16 + (lane & 15);
    short8 v;
    #pragma unroll
    for (int j = 0; j < 8; ++j) v[j] = (short)f2bf(W_hh[(k0 + j) * HDIM + col]);
    *(short8*)(Wf + (size_t)idx * 8) = v;
}

__global__ __launch_bounds__(256, 1) void rnn_steps_k(
    const int* __restrict__ x, const unsigned short* __restrict__ Wf,
    const float* __restrict__ proj, unsigned short* __restrict__ stbf,
    float* __restrict__ stf, unsigned int* __restrict__ flags,
    unsigned int* __restrict__ xcdmap, unsigned int* __restrict__ setupf)
{
    const int bid = blockIdx.x;
    // bid%8 round-robin puts group g's 16 wgs on XCD g>>1 (heuristic; verified
    // at runtime below — correctness does not depend on it)
    const int g   = ((bid & 7) << 1) | ((bid >> 3) & 1);   // 0..15 batch-group
    const int wgn = bid >> 4;                              // 0..15 col-block
    const int tid = threadIdx.x;
    const int wave = tid >> 6, lane = tid & 63;
    const int b0 = g << 4;
    const int nt = (wgn << 2) + wave;      // global 16-col tile index
    const int n0 = nt << 4;                // col base (per wave)
    const int wg_n0 = wgn << 6;            // col base (per workgroup)
    const int row = lane & 15;
    const int kl  = lane >> 4;

    __shared__ __align__(16) char Abuf[32768];     // 16 x 1024 bf16 (swizzled)
    __shared__ unsigned char xl[S_LEN * 16];
    __shared__ float pl[NVOC * 64];
    __shared__ unsigned uni_sh;

    // --- XCD detection + group-uniformity check (once) ---
    unsigned xcd;
    asm("s_getreg_b32 %0, hwreg(HW_REG_XCC_ID)" : "=s"(xcd));
    if (tid == 0) {
        xcdmap[(g << 4) + wgn] = xcd;
        __hip_atomic_fetch_add(setupf + g, 1u, __ATOMIC_RELEASE, __HIP_MEMORY_SCOPE_AGENT);
        while (__hip_atomic_load(setupf + g, __ATOMIC_ACQUIRE, __HIP_MEMORY_SCOPE_AGENT) < 16u) {}
        unsigned u = 1u;
        for (int i = 0; i < 16; ++i) {
            unsigned v = __hip_atomic_load(xcdmap + (g << 4) + i,
                                           __ATOMIC_RELAXED, __HIP_MEMORY_SCOPE_AGENT);
            u &= (unsigned)(v == xcd);
        }
        uni_sh = u;
    }

    for (int i = tid; i < S_LEN * 16; i += 256)
        xl[i] = (unsigned char)x[((i >> 4) << 8) + b0 + (i & 15)];
    for (int i = tid; i < NVOC * 64; i += 256)
        pl[i] = proj[(i >> 6) * HDIM + wg_n0 + (i & 63)];

    // B fragments: wave's K=1024 x 16-col slice of W_hh, resident in regs
    short8 bfr[32];
    const short8* wp = (const short8*)Wf;
    #pragma unroll
    for (int kk = 0; kk < 32; ++kk)
        bfr[kk] = wp[((nt << 5) + kk) * 64 + lane];

    __syncthreads();
    const bool uniform = (uni_sh != 0u);

    const int sw = (row & 7) << 4;   // XOR swizzle (bank-conflict fix)
    const int abase = row << 11;
    const int klb = kl << 4;

    for (int s = 0; s < S_LEN; ++s) {
        f32x4 acc0 = {0.f, 0.f, 0.f, 0.f};
        f32x4 acc1 = acc0, acc2 = acc0, acc3 = acc0;
        if (s > 0) {
            // wave 0 polls the single 64B flag line of step s-1: lane reads
            // slot (lane&15) -> one coalesced L2 transaction per iteration
            if (wave == 0) {
                const unsigned int* fp =
                    flags + (((g << 9) + (s - 1)) << 4) + (lane & 15);
                unsigned v;
                do {
                    v = __hip_atomic_load(fp, __ATOMIC_RELAXED, __HIP_MEMORY_SCOPE_AGENT);
                } while (__any((int)(v == 0u)));
            }
            __syncthreads();
            // stage prev state tile (16 rows x 2048 B), pre-swizzled source
            const char* src = (const char*)stbf + (((s - 1) & 1) << 19) + (g << 15);
            if (uniform) {
                // FAST: producers share this XCD's L2 -> SC0 only (bypass L1)
                #pragma unroll
                for (int it = 0; it < 8; ++it) {
                    int o = (it * 256 + tid) * 16;
                    int arow = o >> 11;
                    int soff = (arow << 11) + ((o & 2047) ^ ((arow & 7) << 4));
                    __builtin_amdgcn_global_load_lds(
                        (const __attribute__((address_space(1))) void*)(src + soff),
                        (__attribute__((address_space(3))) void*)(Abuf + it * 4096 + wave * 1024),
                        16, 0, 1);
                }
            } else {
                // FALLBACK: cross-XCD -> read MALL (SC0|SC1), R5-proven
                #pragma unroll
                for (int it = 0; it < 8; ++it) {
                    int o = (it * 256 + tid) * 16;
                    int arow = o >> 11;
                    int soff = (arow << 11) + ((o & 2047) ^ ((arow & 7) << 4));
                    __builtin_amdgcn_global_load_lds(
                        (const __attribute__((address_space(1))) void*)(src + soff),
                        (__attribute__((address_space(3))) void*)(Abuf + it * 4096 + wave * 1024),
                        16, 0, 17);
                }
            }
            __syncthreads();
            #pragma unroll
            for (int kk = 0; kk < 32; kk += 4) {   // 4 independent acc chains
                short8 a0 = *(const short8*)(Abuf + abase + ((((kk + 0) << 6) + klb) ^ sw));
                short8 a1 = *(const short8*)(Abuf + abase + ((((kk + 1) << 6) + klb) ^ sw));
                short8 a2 = *(const short8*)(Abuf + abase + ((((kk + 2) << 6) + klb) ^ sw));
                short8 a3 = *(const short8*)(Abuf + abase + ((((kk + 3) << 6) + klb) ^ sw));
                acc0 = __builtin_amdgcn_mfma_f32_16x16x32_bf16(a0, bfr[kk + 0], acc0, 0, 0, 0);
                acc1 = __builtin_amdgcn_mfma_f32_16x16x32_bf16(a1, bfr[kk + 1], acc1, 0, 0, 0);
                acc2 = __builtin_amdgcn_mfma_f32_16x16x32_bf16(a2, bfr[kk + 2], acc2, 0, 0, 0);
                acc3 = __builtin_amdgcn_mfma_f32_16x16x32_bf16(a3, bfr[kk + 3], acc3, 0, 0, 0);
            }
        }
        f32x4 accs = acc0 + acc1 + acc2 + acc3;
        #pragma unroll
        for (int j = 0; j < 4; ++j) {
            int r = (kl << 2) + j;
            int xv = xl[(s << 4) + r];
            float p = pl[(xv << 6) + (wave << 4) + row];
            float z = accs[j] + p;
            z = fminf(15.f, fmaxf(-15.f, z));
            float e = exp2f(z * 2.885390082f);
            float th = (e - 1.f) / (e + 1.f);
            if (s < S_LEN - 1) {
                stbf[((s & 1) << 18) + ((b0 + r) << 10) + n0 + row] = f2bf(th);
            } else {
                stf[((b0 + r) << 10) + n0 + row] = th;
            }
        }
        if (s < S_LEN - 1) {
            __syncthreads();  // drains all waves' stores (vmcnt0 before barrier)
            if (tid == 0) {
                // parallel signal: plain store to own 4B slot of the step line
                unsigned int* slot = flags + (((g << 9) + s) << 4) + wgn;
                if (uniform) {
                    __hip_atomic_store(slot, 1u,
                                       __ATOMIC_RELAXED, __HIP_MEMORY_SCOPE_AGENT);
                } else {
                    __hip_atomic_store(slot, 1u,
                                       __ATOMIC_RELEASE, __HIP_MEMORY_SCOPE_AGENT);
                }
            }
        }
    }
}

// out[b][c] = state_f32[b] @ W_ph[:,c] + b_p[c]
__global__ void outproj_k(const float* __restrict__ stf, const float* __restrict__ W_ph,
                          const float* __restrict__ b_p, float* __restrict__ out) {
    int b = blockIdx.x, t = threadIdx.x;
    float acc[10];
    #pragma unroll
    for (int c = 0; c < 10; ++c) acc[c] = 0.f;
    for (int h = t; h < HDIM; h += 256) {
        float sv = stf[b * HDIM + h];
        const float* w = W_ph + h * 10;
        #pragma unroll
        for (int c = 0; c < 10; ++c) acc[c] += sv * w[c];
    }
    __shared__ float red[256][10];
    #pragma unroll
    for (int c = 0; c < 10; ++c) red[t][c] = acc[c];
    __syncthreads();
    for (int off = 128; off > 0; off >>= 1) {
        if (t < off) {
            #pragma unroll
            for (int c = 0; c < 10; ++c) red[t][c] += red[t + off][c];
        }
        __syncthreads();
    }
    if (t < 10) out[b * 10 + t] = red[0][t] + b_p[t];
}

extern "C" void kernel_launch(void* const* d_in, const int* in_sizes, int n_in,
                              void* d_out, int out_size, void* d_ws, size_t ws_size,
                              hipStream_t stream) {
    const int*   x    = (const int*)d_in[0];
    const float* emb  = (const float*)d_in[1];
    const float* W_hx = (const float*)d_in[2];
    const float* W_hh = (const float*)d_in[3];
    const float* W_ph = (const float*)d_in[4];
    const float* b_h  = (const float*)d_in[5];
    const float* b_p  = (const float*)d_in[6];

    char* ws = (char*)d_ws;
    unsigned short* Wf     = (unsigned short*)(ws + OFF_WF);
    float*          proj   = (float*)(ws + OFF_PROJ);
    unsigned short* stbf   = (unsigned short*)(ws + OFF_STBF);
    float*          stf    = (float*)(ws + OFF_STF);
    unsigned int*   flags  = (unsigned int*)(ws + OFF_FLAGS);
    unsigned int*   xcdmap = (unsigned int*)(ws + OFF_XCD);
    unsigned int*   setupf = (unsigned int*)(ws + OFF_SETUP);

    proj_k<<<40, 256, 0, stream>>>(emb, W_hx, b_h, proj);
    packw_k<<<512, 256, 0, stream>>>(W_hh, Wf, flags, xcdmap);
    rnn_steps_k<<<256, 256, 0, stream>>>(x, Wf, proj, stbf, stf, flags, xcdmap, setupf);
    outproj_k<<<256, 256, 0, stream>>>(stf, W_ph, b_p, (float*)d_out);
}

// Round 13
// 1139.032 us; speedup vs baseline: 1.6832x; 1.0773x over previous
//
#include <hip/hip_runtime.h>
#include <hip/hip_bf16.h>

// VanillaRNN: S=512,B=256,E=256,H=1024,C=10, vocab=10
// FINAL = R6 (champion, 2.3us/step): XCD-detected dual protocol.
//  - 16 groups (16 batch rows) x 16 wgs (64 cols) x 256 thr; W_hh fragment-
//    packed, each wave's 16-col x K=1024 slice resident in 128 VGPRs
//  - per step: tid0 RELAXED poll of one RMW counter -> barrier -> 32KB
//    global_load_lds staging (SC0 fast / SC0|SC1 cross-XCD fallback) ->
//    barrier -> 32 MFMA -> tanh epilogue -> barrier (drain) -> RMW signal
//    (RELAXED at shared XCD L2 / RELEASE cross-XCD)
// Structural floor: 512 sequential 16-wg rendezvous; each = drain + signal
// visibility + detect + 32KB L2 fetch + 3 barriers + compute ~= 2.3us.
// R3/R7/R8/R9/R10/R11/R12 protocol variants all regressed vs this.

typedef __attribute__((ext_vector_type(8))) short short8;
typedef __attribute__((ext_vector_type(4))) float f32x4;

#define S_LEN 512
#define HDIM  1024
#define NVOC  10

// ws layout (bytes)
#define OFF_WF    0u          // 1024*1024 bf16 frag-packed = 2 MB
#define OFF_PROJ  2097152u    // 10*1024 f32
#define OFF_STBF  2138112u    // 2 x 256*1024 bf16 (ping-pong)
#define OFF_STF   3186688u    // 256*1024 f32
#define OFF_FLAGS 4235264u    // 16 groups * 512 steps u32
#define OFF_XCD   4268032u    // 16*16 u32 xcd map
#define OFF_SETUP 4269056u    // 16 u32 setup counters

__global__ void zero_flags_k(unsigned int* flags) {
    int id = blockIdx.x * 256 + threadIdx.x;
    if (id < 16 * S_LEN + 256 + 16) flags[id] = 0u;   // flags + xcdmap + setup
}

// proj[v][h] = sum_e emb[v][e]*W_hx[e][h] + b_h[h]
__global__ void proj_k(const float* __restrict__ emb, const float* __restrict__ W_hx,
                       const float* __restrict__ b_h, float* __restrict__ proj) {
    int id = blockIdx.x * 256 + threadIdx.x;
    if (id >= NVOC * HDIM) return;
    int v = id >> 10, h = id & 1023;
    float a = b_h[h];
    #pragma unroll 8
    for (int e = 0; e < 256; ++e) a += emb[v * 256 + e] * W_hx[e * HDIM + h];
    proj[id] = a;
}

static __device__ inline unsigned short f2bf(float f) {
    unsigned u = __builtin_bit_cast(unsigned, f);
    return (unsigned short)((u + 0x7fffu + ((u >> 16) & 1u)) >> 16);
}

// pack W_hh[k][n] (f32) -> Wf frag layout: [nt(64)][kk(32)][lane(64)][8] bf16
__global__ void packw_k(const float* __restrict__ W_hh, unsigned short* __restrict__ Wf) {
    int idx = blockIdx.x * 256 + threadIdx.x;   // 131072 total
    int lane = idx & 63, kk = (idx >> 6) & 31, nt = idx >> 11;
    int k0 = kk * 32 + (lane >> 4) * 8;
    int col = nt * 16 + (lane & 15);
    short8 v;
    #pragma unroll
    for (int j = 0; j < 8; ++j) v[j] = (short)f2bf(W_hh[(k0 + j) * HDIM + col]);
    *(short8*)(Wf + (size_t)idx * 8) = v;
}

__global__ __launch_bounds__(256, 1) void rnn_steps_k(
    const int* __restrict__ x, const unsigned short* __restrict__ Wf,
    const float* __restrict__ proj, unsigned short* __restrict__ stbf,
    float* __restrict__ stf, unsigned int* __restrict__ flags,
    unsigned int* __restrict__ xcdmap, unsigned int* __restrict__ setupf)
{
    const int bid = blockIdx.x;
    // bid%8 round-robin puts group g's 16 wgs on XCD g>>1 (heuristic; verified
    // at runtime below — correctness does not depend on it)
    const int g   = ((bid & 7) << 1) | ((bid >> 3) & 1);   // 0..15 batch-group
    const int wgn = bid >> 4;                              // 0..15 col-block
    const int tid = threadIdx.x;
    const int wave = tid >> 6, lane = tid & 63;
    const int b0 = g << 4;
    const int nt = (wgn << 2) + wave;      // global 16-col tile index
    const int n0 = nt << 4;                // col base (per wave)
    const int wg_n0 = wgn << 6;            // col base (per workgroup)
    const int row = lane & 15;
    const int kl  = lane >> 4;

    __shared__ __align__(16) char Abuf[32768];     // 16 x 1024 bf16 (swizzled)
    __shared__ unsigned char xl[S_LEN * 16];
    __shared__ float pl[NVOC * 64];
    __shared__ unsigned uni_sh;

    // --- XCD detection + group-uniformity check (once) ---
    unsigned xcd;
    asm("s_getreg_b32 %0, hwreg(HW_REG_XCC_ID)" : "=s"(xcd));
    if (tid == 0) {
        xcdmap[(g << 4) + wgn] = xcd;
        __hip_atomic_fetch_add(setupf + g, 1u, __ATOMIC_RELEASE, __HIP_MEMORY_SCOPE_AGENT);
        while (__hip_atomic_load(setupf + g, __ATOMIC_ACQUIRE, __HIP_MEMORY_SCOPE_AGENT) < 16u) {}
        unsigned u = 1u;
        for (int i = 0; i < 16; ++i) {
            unsigned v = __hip_atomic_load(xcdmap + (g << 4) + i,
                                           __ATOMIC_RELAXED, __HIP_MEMORY_SCOPE_AGENT);
            u &= (unsigned)(v == xcd);
        }
        uni_sh = u;
    }

    for (int i = tid; i < S_LEN * 16; i += 256)
        xl[i] = (unsigned char)x[((i >> 4) << 8) + b0 + (i & 15)];
    for (int i = tid; i < NVOC * 64; i += 256)
        pl[i] = proj[(i >> 6) * HDIM + wg_n0 + (i & 63)];

    // B fragments: wave's K=1024 x 16-col slice of W_hh, resident in regs
    short8 bfr[32];
    const short8* wp = (const short8*)Wf;
    #pragma unroll
    for (int kk = 0; kk < 32; ++kk)
        bfr[kk] = wp[((nt << 5) + kk) * 64 + lane];

    __syncthreads();
    const bool uniform = (uni_sh != 0u);

    const int sw = (row & 7) << 4;   // XOR swizzle (bank-conflict fix)
    const int abase = row << 11;
    const int klb = kl << 4;

    for (int s = 0; s < S_LEN; ++s) {
        f32x4 acc0 = {0.f, 0.f, 0.f, 0.f};
        f32x4 acc1 = acc0, acc2 = acc0, acc3 = acc0;
        if (s > 0) {
            if (tid == 0) {
                const unsigned int* fp = flags + (g << 9) + (s - 1);
                // relaxed poll (atomic load bypasses L1; L2-resident fast path)
                while (__hip_atomic_load(fp, __ATOMIC_RELAXED, __HIP_MEMORY_SCOPE_AGENT) < 16u) {}
            }
            __syncthreads();
            const char* src = (const char*)stbf + (((s - 1) & 1) << 19) + (g << 15);
            if (uniform) {
                // FAST: producers share this XCD's L2 -> SC0 only (bypass L1)
                #pragma unroll
                for (int it = 0; it < 8; ++it) {
                    int o = (it * 256 + tid) * 16;
                    int arow = o >> 11;
                    int soff = (arow << 11) + ((o & 2047) ^ ((arow & 7) << 4));
                    __builtin_amdgcn_global_load_lds(
                        (const __attribute__((address_space(1))) void*)(src + soff),
                        (__attribute__((address_space(3))) void*)(Abuf + it * 4096 + wave * 1024),
                        16, 0, 1);
                }
            } else {
                // FALLBACK: cross-XCD -> read MALL (SC0|SC1), R5-proven
                #pragma unroll
                for (int it = 0; it < 8; ++it) {
                    int o = (it * 256 + tid) * 16;
                    int arow = o >> 11;
                    int soff = (arow << 11) + ((o & 2047) ^ ((arow & 7) << 4));
                    __builtin_amdgcn_global_load_lds(
                        (const __attribute__((address_space(1))) void*)(src + soff),
                        (__attribute__((address_space(3))) void*)(Abuf + it * 4096 + wave * 1024),
                        16, 0, 17);
                }
            }
            __syncthreads();
            #pragma unroll
            for (int kk = 0; kk < 32; kk += 4) {   // 4 independent acc chains
                short8 a0 = *(const short8*)(Abuf + abase + ((((kk + 0) << 6) + klb) ^ sw));
                short8 a1 = *(const short8*)(Abuf + abase + ((((kk + 1) << 6) + klb) ^ sw));
                short8 a2 = *(const short8*)(Abuf + abase + ((((kk + 2) << 6) + klb) ^ sw));
                short8 a3 = *(const short8*)(Abuf + abase + ((((kk + 3) << 6) + klb) ^ sw));
                acc0 = __builtin_amdgcn_mfma_f32_16x16x32_bf16(a0, bfr[kk + 0], acc0, 0, 0, 0);
                acc1 = __builtin_amdgcn_mfma_f32_16x16x32_bf16(a1, bfr[kk + 1], acc1, 0, 0, 0);
                acc2 = __builtin_amdgcn_mfma_f32_16x16x32_bf16(a2, bfr[kk + 2], acc2, 0, 0, 0);
                acc3 = __builtin_amdgcn_mfma_f32_16x16x32_bf16(a3, bfr[kk + 3], acc3, 0, 0, 0);
            }
        }
        f32x4 accs = acc0 + acc1 + acc2 + acc3;
        #pragma unroll
        for (int j = 0; j < 4; ++j) {
            int r = (kl << 2) + j;
            int xv = xl[(s << 4) + r];
            float p = pl[(xv << 6) + (wave << 4) + row];
            float z = accs[j] + p;
            z = fminf(15.f, fmaxf(-15.f, z));
            float e = exp2f(z * 2.885390082f);
            float th = (e - 1.f) / (e + 1.f);
            if (s < S_LEN - 1) {
                stbf[((s & 1) << 18) + ((b0 + r) << 10) + n0 + row] = f2bf(th);
            } else {
                stf[((b0 + r) << 10) + n0 + row] = th;
            }
        }
        if (s < S_LEN - 1) {
            __syncthreads();  // drains all waves' stores (vmcnt0 before barrier)
            if (tid == 0) {
                if (uniform) {
                    // same-XCD: state visible in shared L2 after drain
                    __hip_atomic_fetch_add(flags + (g << 9) + s, 1u,
                                           __ATOMIC_RELAXED, __HIP_MEMORY_SCOPE_AGENT);
                } else {
                    // cross-XCD: release pushes state to MALL first
                    __hip_atomic_fetch_add(flags + (g << 9) + s, 1u,
                                           __ATOMIC_RELEASE, __HIP_MEMORY_SCOPE_AGENT);
                }
            }
        }
    }
}

// out[b][c] = state_f32[b] @ W_ph[:,c] + b_p[c]
__global__ void outproj_k(const float* __restrict__ stf, const float* __restrict__ W_ph,
                          const float* __restrict__ b_p, float* __restrict__ out) {
    int b = blockIdx.x, t = threadIdx.x;
    float acc[10];
    #pragma unroll
    for (int c = 0; c < 10; ++c) acc[c] = 0.f;
    for (int h = t; h < HDIM; h += 256) {
        float sv = stf[b * HDIM + h];
        const float* w = W_ph + h * 10;
        #pragma unroll
        for (int c = 0; c < 10; ++c) acc[c] += sv * w[c];
    }
    __shared__ float red[256][10];
    #pragma unroll
    for (int c = 0; c < 10; ++c) red[t][c] = acc[c];
    __syncthreads();
    for (int off = 128; off > 0; off >>= 1) {
        if (t < off) {
            #pragma unroll
            for (int c = 0; c < 10; ++c) red[t][c] += red[t + off][c];
        }
        __syncthreads();
    }
    if (t < 10) out[b * 10 + t] = red[0][t] + b_p[t];
}

extern "C" void kernel_launch(void* const* d_in, const int* in_sizes, int n_in,
                              void* d_out, int out_size, void* d_ws, size_t ws_size,
                              hipStream_t stream) {
    const int*   x    = (const int*)d_in[0];
    const float* emb  = (const float*)d_in[1];
    const float* W_hx = (const float*)d_in[2];
    const float* W_hh = (const float*)d_in[3];
    const float* W_ph = (const float*)d_in[4];
    const float* b_h  = (const float*)d_in[5];
    const float* b_p  = (const float*)d_in[6];

    char* ws = (char*)d_ws;
    unsigned short* Wf     = (unsigned short*)(ws + OFF_WF);
    float*          proj   = (float*)(ws + OFF_PROJ);
    unsigned short* stbf   = (unsigned short*)(ws + OFF_STBF);
    float*          stf    = (float*)(ws + OFF_STF);
    unsigned int*   flags  = (unsigned int*)(ws + OFF_FLAGS);
    unsigned int*   xcdmap = (unsigned int*)(ws + OFF_XCD);
    unsigned int*   setupf = (unsigned int*)(ws + OFF_SETUP);

    zero_flags_k<<<34, 256, 0, stream>>>(flags);
    proj_k<<<40, 256, 0, stream>>>(emb, W_hx, b_h, proj);
    packw_k<<<512, 256, 0, stream>>>(W_hh, Wf);
    rnn_steps_k<<<256, 256, 0, stream>>>(x, Wf, proj, stbf, stf, flags, xcdmap, setupf);
    outproj_k<<<256, 256, 0, stream>>>(stf, W_ph, b_p, (float*)d_out);
}